// Round 6
// baseline (111.871 us; speedup 1.0000x reference)
//
#include <hip/hip_runtime.h>

// QuantGelu: y = pre_x_int * sigmoid_int * (scaler/128)
//   pre_x_int = clip(round(x/scaler), -128, 127)  [per-channel scaler, D=4096]
//   sigmoid via integer shift-exp over {x_int, -row_max}
//
// Round-6: 2 rows per barrier group (1 barrier/row instead of 2), prefetch
// next pair into the freed xv regs, pre packed as i8x4 + slot bytes + 2^-7
// folded into sig table to stay <=64 VGPR (32 waves/CU). Math identical to
// round 5 -> bit-same output.

#define D 4096
#define BLK 512
#define CPT 8           // BLK*CPT == D
#define RPB 8
#define NW (BLK / 64)
#define NSLOT 12        // x0 slots covered by fast path
#define TENT (NSLOT * 256)
#define EPS 1e-4f
#define F2_31 2147483648.0f   // fl32(2^31 - 1)

typedef float f32x4 __attribute__((ext_vector_type(4)));

// Exact floor(fl(xi/x0)) for integer-valued xi, integer x0 in [-64,-1],
// clamped ratio in [0,15]: divisible case error << EPS; non-divisible case
// distance to integer >= 1/|x0| >= 1/64 >> EPS. ldexpf = v_ldexp_f32; q<0
// (em path) -> inf, matching np.exp2(15-q)=inf, absorbed by min(esum,2^31).
__device__ __forceinline__ float exp_fast(float xi, float nx0, float rx0) {
    const float q = floorf(fmaf(xi, rx0, EPS));
    const float r = fmaf(nx0, q, xi);      // xi - x0*q, exact (small ints)
    const float e = fmaf(r, 0.5f, nx0);    // r/2 - x0, halves, exact
    return floorf(ldexpf(e, 15 - (int)q)); // e > 0 -> max(.,0) redundant
}

// Fully-IEEE path, exact for any x0 (fallback only).
__device__ __forceinline__ float exp_slow(float xi, float x0) {
    xi = fmaxf(xi, 15.0f * x0);
    const float q = floorf(xi / x0);
    const float r = fmaf(-x0, q, xi);
    const float e = fmaf(r, 0.5f, -x0);
    return fmaxf(floorf(e * ldexpf(1.0f, 15 - (int)q)), 0.0f);
}

__global__ __launch_bounds__(BLK, 8) void quantgelu_kernel(
    const float* __restrict__ x, const float* __restrict__ scaler,
    float* __restrict__ out, int nrows)
{
    const int tid  = threadIdx.x;
    const int wid  = tid >> 6;
    const int lane = tid & 63;
    const int row0 = blockIdx.x * RPB;

    __shared__ __align__(16) float smax2[2][NW];
    __shared__ float eit[TENT];
    __shared__ float siga[TENT];
    __shared__ float sigb[TENT];

    const int c0 = tid * 4;
    const int c1 = BLK * 4 + tid * 4;

    // ---- prefetch first pair ASAP (hide under const setup divs) ----
    long long base = (long long)row0 * D;
    float4 xv[4] = {};          // [0..1] row a, [2..3] row b
    if (row0 < nrows) {
        xv[0] = *reinterpret_cast<const float4*>(x + base + c0);
        xv[1] = *reinterpret_cast<const float4*>(x + base + c1);
    }
    if (row0 + 1 < nrows) {
        xv[2] = *reinterpret_cast<const float4*>(x + base + D + c0);
        xv[3] = *reinterpret_cast<const float4*>(x + base + D + c1);
    }

    // ---- per-channel constants (hoisted across RPB rows) ----
    float s_[CPT], rs_[CPT], x0_[CPT];
    #pragma unroll
    for (int k = 0; k < 2; ++k) {
        const float4 sv = *reinterpret_cast<const float4*>(scaler + (k ? c1 : c0));
        const float ss[4] = {sv.x, sv.y, sv.z, sv.w};
        #pragma unroll
        for (int j = 0; j < 4; ++j) {
            const int i = k * 4 + j;
            const float s = ss[j];
            s_[i]  = s;
            rs_[i] = 1.0f / s;                          // Markstein seed
            x0_[i] = floorf(-1.0f / (s * 1.702f));      // IEEE div, 1x/8 rows
        }
    }

    // ---- block-wide x0 range ----
    float x0mn = x0_[0], x0mx = x0_[0];
    #pragma unroll
    for (int i = 1; i < CPT; ++i) {
        x0mn = fminf(x0mn, x0_[i]);
        x0mx = fmaxf(x0mx, x0_[i]);
    }
    #pragma unroll
    for (int off = 1; off < 64; off <<= 1) {
        x0mn = fminf(x0mn, __shfl_xor(x0mn, off));
        x0mx = fmaxf(x0mx, __shfl_xor(x0mx, off));
    }
    if (lane == 0) { smax2[0][wid] = x0mn; smax2[1][wid] = x0mx; }
    __syncthreads();
    #pragma unroll
    for (int w = 0; w < NW; ++w) {
        x0mn = fminf(x0mn, smax2[0][w]);
        x0mx = fmaxf(x0mx, smax2[1][w]);
    }
    __syncthreads();    // smax2 free for row-max reuse

    const int  nslots = (int)(x0mx - x0mn) + 1;
    const bool ok = (x0mn >= -64.0f) && (nslots <= NSLOT);   // block-uniform
    const int  nent = nslots << 8;              // multiple of 256

    // slot ids packed as bytes (clamped before cvt to keep it defined)
    unsigned slotpk[2] = {0u, 0u};
    #pragma unroll
    for (int k = 0; k < 2; ++k)
        #pragma unroll
        for (int j = 0; j < 4; ++j) {
            const float sl = fminf(fmaxf(x0_[k * 4 + j] - x0mn, 0.0f), 255.0f);
            slotpk[k] |= ((unsigned)(int)sl & 0xffu) << (8 * j);
        }
    // x0_ dead from here on the fast path (fallback recomputes from s_)

    // lane-slot constants: lane l serves slot l
    const float x0l  = x0mn + (float)lane;
    const float nx0l = -x0l;
    const float rx0l = 1.0f / x0l;              // IEEE div, 1x per block
    const float c15l = 15.0f * x0l;

    // block-invariant ei table: ei(slot, d) = int_exp_shift(-d, x0_slot)
    if (ok) {
        for (int e = tid; e < nent; e += BLK) {
            const int   slot = e >> 8;
            const float x0v  = x0mn + (float)slot;
            float xi = -(float)(e & 255);
            xi = xi + floorf(xi * 0.5f) - floorf(xi * 0.0625f);
            xi = fmaxf(xi, 15.0f * x0v);
            eit[e] = exp_fast(xi, -x0v, __shfl(rx0l, slot));
        }
    }
    // eit writes ordered before first build's reads by barrier A below.

    for (int g = 0; g < RPB / 2; ++g) {
        const int ra = row0 + 2 * g;
        if (ra >= nrows) break;                 // block-uniform
        const bool bval = (ra + 1) < nrows;

        // phase 1: quantize (Markstein) + row max + i8 pack, both rows
        float va = -INFINITY, vb = -INFINITY;
        unsigned pk[4] = {0u, 0u, 0u, 0u};      // [0..1] row a, [2..3] row b
        #pragma unroll
        for (int k = 0; k < 2; ++k) {
            const float* xa = reinterpret_cast<const float*>(&xv[k]);
            const float* xb = reinterpret_cast<const float*>(&xv[2 + k]);
            #pragma unroll
            for (int j = 0; j < 4; ++j) {
                const int i = k * 4 + j;
                float q0 = xa[j] * rs_[i];
                float rr = fmaf(-s_[i], q0, xa[j]);
                float p  = __builtin_amdgcn_fmed3f(
                               rintf(fmaf(rr, rs_[i], q0)), -128.0f, 127.0f);
                va = fmaxf(va, p);
                pk[k] |= ((unsigned)(int)p & 0xffu) << (8 * j);

                q0 = xb[j] * rs_[i];
                rr = fmaf(-s_[i], q0, xb[j]);
                p  = __builtin_amdgcn_fmed3f(
                               rintf(fmaf(rr, rs_[i], q0)), -128.0f, 127.0f);
                vb = fmaxf(vb, p);
                pk[2 + k] |= ((unsigned)(int)p & 0xffu) << (8 * j);
            }
        }

        // prefetch next pair into freed xv (in flight across reduce+build)
        {
            const long long nb = base + 2 * D;
            if (ra + 2 < nrows) {
                xv[0] = *reinterpret_cast<const float4*>(x + nb + c0);
                xv[1] = *reinterpret_cast<const float4*>(x + nb + c1);
            }
            if (ra + 3 < nrows) {
                xv[2] = *reinterpret_cast<const float4*>(x + nb + D + c0);
                xv[3] = *reinterpret_cast<const float4*>(x + nb + D + c1);
            }
        }

        // 64-lane butterfly max, both rows interleaved
        #pragma unroll
        for (int off = 1; off < 64; off <<= 1) {
            va = fmaxf(va, __shfl_xor(va, off));
            vb = fmaxf(vb, __shfl_xor(vb, off));
        }
        if (lane == 0) { smax2[0][wid] = va; smax2[1][wid] = vb; }
        __syncthreads();                        // A
        {
            const float4 a0 = *reinterpret_cast<const float4*>(&smax2[0][0]);
            const float4 a1 = *reinterpret_cast<const float4*>(&smax2[0][4]);
            const float4 b0 = *reinterpret_cast<const float4*>(&smax2[1][0]);
            const float4 b1 = *reinterpret_cast<const float4*>(&smax2[1][4]);
            va = fmaxf(fmaxf(fmaxf(a0.x, a0.y), fmaxf(a0.z, a0.w)),
                       fmaxf(fmaxf(a1.x, a1.y), fmaxf(a1.z, a1.w)));
            vb = fmaxf(fmaxf(fmaxf(b0.x, b0.y), fmaxf(b0.z, b0.w)),
                       fmaxf(fmaxf(b1.x, b1.y), fmaxf(b1.z, b1.w)));
        }

        const float xma  = -va, xmb = -vb;
        const float xmta = xma + floorf(xma * 0.5f) - floorf(xma * 0.0625f);
        const float xmtb = xmb + floorf(xmb * 0.5f) - floorf(xmb * 0.0625f);

        // per-row sig tables (2^-7 folded in: sig <= 128 integer -> exact)
        if (ok) {
            const float em_al = exp_fast(fmaxf(xmta, c15l), nx0l, rx0l);
            const float em_bl = exp_fast(fmaxf(xmtb, c15l), nx0l, rx0l);
            for (int e = tid; e < nent; e += BLK) {
                const float ei     = eit[e];
                const float em     = __shfl(em_al, e >> 8);
                const float esum   = fminf(ei + em, F2_31);
                const float factor = floorf(F2_31 / esum);        // IEEE div
                siga[e] = floorf((ei * factor) * 0x1p-24f) * 0.0078125f;
            }
            if (bval) {
                for (int e = tid; e < nent; e += BLK) {
                    const float ei     = eit[e];
                    const float em     = __shfl(em_bl, e >> 8);
                    const float esum   = fminf(ei + em, F2_31);
                    const float factor = floorf(F2_31 / esum);    // IEEE div
                    sigb[e] = floorf((ei * factor) * 0x1p-24f) * 0.0078125f;
                }
            }
        }
        __syncthreads();                        // B (unconditional)

        if (ok) {
            const int via = (int)va, vib = (int)vb;
            #pragma unroll
            for (int k = 0; k < 2; ++k) {
                f32x4 ov;
                #pragma unroll
                for (int j = 0; j < 4; ++j) {
                    const int pi   = (int)(signed char)((pk[k] >> (8 * j)) & 0xffu);
                    const int slot = (int)((slotpk[k] >> (8 * j)) & 0xffu);
                    const float sg = siga[(slot << 8) + (via - pi)];
                    ov[j] = ((float)pi * sg) * s_[k * 4 + j];
                }
                __builtin_nontemporal_store(
                    ov, reinterpret_cast<f32x4*>(out + base + (k ? c1 : c0)));
            }
            if (bval) {
                #pragma unroll
                for (int k = 0; k < 2; ++k) {
                    f32x4 ov;
                    #pragma unroll
                    for (int j = 0; j < 4; ++j) {
                        const int pi   = (int)(signed char)((pk[2 + k] >> (8 * j)) & 0xffu);
                        const int slot = (int)((slotpk[k] >> (8 * j)) & 0xffu);
                        const float sg = sigb[(slot << 8) + (vib - pi)];
                        ov[j] = ((float)pi * sg) * s_[k * 4 + j];
                    }
                    __builtin_nontemporal_store(
                        ov, reinterpret_cast<f32x4*>(out + base + D + (k ? c1 : c0)));
                }
            }
        } else {
            // rare block-uniform exact fallback (x0 out of table range)
            #pragma unroll
            for (int k = 0; k < 2; ++k) {
                f32x4 ov, ow;
                #pragma unroll
                for (int j = 0; j < 4; ++j) {
                    const int i = k * 4 + j;
                    const float x0 = floorf(-1.0f / (s_[i] * 1.702f));
                    const float s128 = s_[i] * 0.0078125f;
                    // row a
                    {
                        const float p = (float)(int)(signed char)((pk[k] >> (8 * j)) & 0xffu);
                        float xi = p - va;
                        xi = xi + floorf(xi * 0.5f) - floorf(xi * 0.0625f);
                        const float ei = exp_slow(xi, x0);
                        const float em = exp_slow(xmta, x0);
                        const float esum   = fminf(ei + em, F2_31);
                        const float factor = floorf(F2_31 / esum);
                        const float sig    = floorf((ei * factor) * 0x1p-24f);
                        ov[j] = (p * sig) * s128;
                    }
                    // row b
                    {
                        const float p = (float)(int)(signed char)((pk[2 + k] >> (8 * j)) & 0xffu);
                        float xi = p - vb;
                        xi = xi + floorf(xi * 0.5f) - floorf(xi * 0.0625f);
                        const float ei = exp_slow(xi, x0);
                        const float em = exp_slow(xmtb, x0);
                        const float esum   = fminf(ei + em, F2_31);
                        const float factor = floorf(F2_31 / esum);
                        const float sig    = floorf((ei * factor) * 0x1p-24f);
                        ow[j] = (p * sig) * s128;
                    }
                }
                __builtin_nontemporal_store(
                    ov, reinterpret_cast<f32x4*>(out + base + (k ? c1 : c0)));
                if (bval)
                    __builtin_nontemporal_store(
                        ow, reinterpret_cast<f32x4*>(out + base + D + (k ? c1 : c0)));
            }
        }

        base += 2 * D;
    }
}

extern "C" void kernel_launch(void* const* d_in, const int* in_sizes, int n_in,
                              void* d_out, int out_size, void* d_ws, size_t ws_size,
                              hipStream_t stream) {
    const float* x      = (const float*)d_in[0];
    const float* scaler = (const float*)d_in[1];
    float* out          = (float*)d_out;

    const int nrows = in_sizes[0] / D;                 // 8192
    const int grid  = (nrows + RPB - 1) / RPB;         // 1024
    quantgelu_kernel<<<grid, BLK, 0, stream>>>(x, scaler, out, nrows);
}

// Round 7
// 53.075 us; speedup vs baseline: 2.1078x; 2.1078x over previous
//
#include <hip/hip_runtime.h>

// QuantGelu: y = pre_x_int * sigmoid_int * (scaler/128)
//   pre_x_int = clip(round(x/scaler), -128, 127)  [per-channel scaler, D=4096]
//   sigmoid via integer shift-exp over {x_int, -row_max}
//
// Round-7: round-5 structure + 2 rows per barrier group (8 barriers/block
// instead of 16) with a fused dual-row sig build. NO forced min-occupancy
// launch bound and NO byte packing (round-6's 32-VGPR spill regression).
// Math identical to rounds 4-6 -> bit-same output.

#define D 4096
#define BLK 512
#define CPT 8           // BLK*CPT == D
#define RPB 8
#define NW (BLK / 64)
#define NSLOT 12        // x0 slots covered by fast path
#define TENT (NSLOT * 256)
#define EPS 1e-4f
#define F2_31 2147483648.0f   // fl32(2^31 - 1)

typedef float f32x4 __attribute__((ext_vector_type(4)));

// Exact floor(fl(xi/x0)) for integer-valued xi, integer x0 in [-64,-1],
// clamped ratio in [0,15]: divisible case error << EPS; non-divisible case
// distance to integer >= 1/|x0| >= 1/64 >> EPS. ldexpf = v_ldexp_f32; q<0
// (em path) -> inf, matching np.exp2(15-q)=inf, absorbed by min(esum,2^31).
__device__ __forceinline__ float exp_fast(float xi, float nx0, float rx0) {
    const float q = floorf(fmaf(xi, rx0, EPS));
    const float r = fmaf(nx0, q, xi);      // xi - x0*q, exact (small ints)
    const float e = fmaf(r, 0.5f, nx0);    // r/2 - x0, halves, exact
    return floorf(ldexpf(e, 15 - (int)q)); // e > 0 -> max(.,0) redundant
}

// Fully-IEEE path, exact for any x0 (fallback only).
__device__ __forceinline__ float exp_slow(float xi, float x0) {
    xi = fmaxf(xi, 15.0f * x0);
    const float q = floorf(xi / x0);
    const float r = fmaf(-x0, q, xi);
    const float e = fmaf(r, 0.5f, -x0);
    return fmaxf(floorf(e * ldexpf(1.0f, 15 - (int)q)), 0.0f);
}

__global__ __launch_bounds__(BLK) void quantgelu_kernel(
    const float* __restrict__ x, const float* __restrict__ scaler,
    float* __restrict__ out, int nrows)
{
    const int tid  = threadIdx.x;
    const int wid  = tid >> 6;
    const int lane = tid & 63;
    const int row0 = blockIdx.x * RPB;

    __shared__ __align__(16) float smax2[2][NW];
    __shared__ float eit[TENT];
    __shared__ float siga[TENT];
    __shared__ float sigb[TENT];

    const int c0 = tid * 4;
    const int c1 = BLK * 4 + tid * 4;

    // ---- prefetch first pair ASAP (hide under const-setup divs) ----
    long long base = (long long)row0 * D;
    float4 xv[4];          // [0..1] row a, [2..3] row b
    if (row0 < nrows) {
        xv[0] = *reinterpret_cast<const float4*>(x + base + c0);
        xv[1] = *reinterpret_cast<const float4*>(x + base + c1);
    }
    if (row0 + 1 < nrows) {
        xv[2] = *reinterpret_cast<const float4*>(x + base + D + c0);
        xv[3] = *reinterpret_cast<const float4*>(x + base + D + c1);
    }

    // ---- per-channel constants (hoisted across RPB rows) ----
    float s_[CPT], rs_[CPT], x0_[CPT];
    #pragma unroll
    for (int k = 0; k < 2; ++k) {
        const float4 sv = *reinterpret_cast<const float4*>(scaler + (k ? c1 : c0));
        const float ss[4] = {sv.x, sv.y, sv.z, sv.w};
        #pragma unroll
        for (int j = 0; j < 4; ++j) {
            const int i = k * 4 + j;
            const float s = ss[j];
            s_[i]  = s;
            rs_[i] = 1.0f / s;                          // Markstein seed
            x0_[i] = floorf(-1.0f / (s * 1.702f));      // IEEE div, 1x/8 rows
        }
    }

    // ---- block-wide x0 range ----
    float x0mn = x0_[0], x0mx = x0_[0];
    #pragma unroll
    for (int i = 1; i < CPT; ++i) {
        x0mn = fminf(x0mn, x0_[i]);
        x0mx = fmaxf(x0mx, x0_[i]);
    }
    #pragma unroll
    for (int off = 1; off < 64; off <<= 1) {
        x0mn = fminf(x0mn, __shfl_xor(x0mn, off));
        x0mx = fmaxf(x0mx, __shfl_xor(x0mx, off));
    }
    if (lane == 0) { smax2[0][wid] = x0mn; smax2[1][wid] = x0mx; }
    __syncthreads();
    #pragma unroll
    for (int w = 0; w < NW; ++w) {
        x0mn = fminf(x0mn, smax2[0][w]);
        x0mx = fmaxf(x0mx, smax2[1][w]);
    }
    __syncthreads();    // smax2 free for row-max reuse

    const int  nslots = (int)(x0mx - x0mn) + 1;
    const bool ok = (x0mn >= -64.0f) && (nslots <= NSLOT);   // block-uniform
    const int  nent = nslots << 8;              // multiple of 256

    int bo_[CPT];
    #pragma unroll
    for (int i = 0; i < CPT; ++i)
        bo_[i] = ((int)(x0_[i] - x0mn)) << 8;   // garbage if !ok, unused there

    // lane-slot constants: lane l serves slot l
    const float x0l  = x0mn + (float)lane;
    const float nx0l = -x0l;
    const float rx0l = 1.0f / x0l;              // IEEE div, 1x per block
    const float c15l = 15.0f * x0l;

    // block-invariant ei table: ei(slot, d) = int_exp_shift(-d, x0_slot)
    if (ok) {
        for (int e = tid; e < nent; e += BLK) {
            const int   slot = e >> 8;
            const float x0v  = x0mn + (float)slot;
            float xi = -(float)(e & 255);
            xi = xi + floorf(xi * 0.5f) - floorf(xi * 0.0625f);
            xi = fmaxf(xi, 15.0f * x0v);
            eit[e] = exp_fast(xi, -x0v, __shfl(rx0l, slot));
        }
    }
    // eit writes ordered before first build's reads by barrier A below.

    for (int g = 0; g < RPB / 2; ++g) {
        const int ra = row0 + 2 * g;
        if (ra >= nrows) break;                 // block-uniform
        const bool bval = (ra + 1) < nrows;

        // phase 1: quantize (Markstein correctly-rounded div) + row max
        float pa[CPT], pb[CPT];
        float va = -INFINITY, vb = -INFINITY;
        #pragma unroll
        for (int k = 0; k < 2; ++k) {
            const float* xa = reinterpret_cast<const float*>(&xv[k]);
            const float* xb = reinterpret_cast<const float*>(&xv[2 + k]);
            #pragma unroll
            for (int j = 0; j < 4; ++j) {
                const int i = k * 4 + j;
                float q0 = xa[j] * rs_[i];
                float rr = fmaf(-s_[i], q0, xa[j]);
                float p  = __builtin_amdgcn_fmed3f(
                               rintf(fmaf(rr, rs_[i], q0)), -128.0f, 127.0f);
                pa[i] = p;
                va = fmaxf(va, p);

                q0 = xb[j] * rs_[i];
                rr = fmaf(-s_[i], q0, xb[j]);
                p  = __builtin_amdgcn_fmed3f(
                               rintf(fmaf(rr, rs_[i], q0)), -128.0f, 127.0f);
                pb[i] = p;
                vb = fmaxf(vb, p);
            }
        }

        // prefetch next pair into freed xv (in flight across reduce+build)
        {
            const long long nb = base + 2 * D;
            if (ra + 2 < nrows) {
                xv[0] = *reinterpret_cast<const float4*>(x + nb + c0);
                xv[1] = *reinterpret_cast<const float4*>(x + nb + c1);
            }
            if (ra + 3 < nrows) {
                xv[2] = *reinterpret_cast<const float4*>(x + nb + D + c0);
                xv[3] = *reinterpret_cast<const float4*>(x + nb + D + c1);
            }
        }

        // 64-lane butterfly max, both rows interleaved
        #pragma unroll
        for (int off = 1; off < 64; off <<= 1) {
            va = fmaxf(va, __shfl_xor(va, off));
            vb = fmaxf(vb, __shfl_xor(vb, off));
        }
        if (lane == 0) { smax2[0][wid] = va; smax2[1][wid] = vb; }
        __syncthreads();                        // A
        {
            const float4 a0 = *reinterpret_cast<const float4*>(&smax2[0][0]);
            const float4 a1 = *reinterpret_cast<const float4*>(&smax2[0][4]);
            const float4 b0 = *reinterpret_cast<const float4*>(&smax2[1][0]);
            const float4 b1 = *reinterpret_cast<const float4*>(&smax2[1][4]);
            va = fmaxf(fmaxf(fmaxf(a0.x, a0.y), fmaxf(a0.z, a0.w)),
                       fmaxf(fmaxf(a1.x, a1.y), fmaxf(a1.z, a1.w)));
            vb = fmaxf(fmaxf(fmaxf(b0.x, b0.y), fmaxf(b0.z, b0.w)),
                       fmaxf(fmaxf(b1.x, b1.y), fmaxf(b1.z, b1.w)));
        }

        const float xma  = -va, xmb = -vb;
        const float xmta = xma + floorf(xma * 0.5f) - floorf(xma * 0.0625f);
        const float xmtb = xmb + floorf(xmb * 0.5f) - floorf(xmb * 0.0625f);

        // fused per-row sig tables (scaler/128's 2^-7 folded in: sig integer
        // <= 256 -> *2^-7 exact)
        if (ok) {
            const float em_al = exp_fast(fmaxf(xmta, c15l), nx0l, rx0l);
            const float em_bl = bval ? exp_fast(fmaxf(xmtb, c15l), nx0l, rx0l) : 0.0f;
            for (int e = tid; e < nent; e += BLK) {
                const int   slot = e >> 8;      // wave-uniform (64 | 256)
                const float ei   = eit[e];
                const float ema  = __shfl(em_al, slot);
                const float emb  = __shfl(em_bl, slot);
                const float fa = floorf(F2_31 / fminf(ei + ema, F2_31)); // IEEE div
                const float fb = floorf(F2_31 / fminf(ei + emb, F2_31)); // IEEE div
                siga[e] = floorf((ei * fa) * 0x1p-24f) * 0.0078125f;
                sigb[e] = floorf((ei * fb) * 0x1p-24f) * 0.0078125f;
            }
        }
        __syncthreads();                        // B (unconditional)

        if (ok) {
            #pragma unroll
            for (int k = 0; k < 2; ++k) {
                f32x4 ov;
                #pragma unroll
                for (int j = 0; j < 4; ++j) {
                    const int i = k * 4 + j;
                    const int d = (int)(va - pa[i]);        // exact, [0,255]
                    ov[j] = (pa[i] * siga[bo_[i] + d]) * s_[i];
                }
                __builtin_nontemporal_store(
                    ov, reinterpret_cast<f32x4*>(out + base + (k ? c1 : c0)));
            }
            if (bval) {
                #pragma unroll
                for (int k = 0; k < 2; ++k) {
                    f32x4 ov;
                    #pragma unroll
                    for (int j = 0; j < 4; ++j) {
                        const int i = k * 4 + j;
                        const int d = (int)(vb - pb[i]);    // exact, [0,255]
                        ov[j] = (pb[i] * sigb[bo_[i] + d]) * s_[i];
                    }
                    __builtin_nontemporal_store(
                        ov, reinterpret_cast<f32x4*>(out + base + D + (k ? c1 : c0)));
                }
            }
        } else {
            // rare block-uniform exact fallback (x0 out of table range)
            #pragma unroll
            for (int k = 0; k < 2; ++k) {
                f32x4 ov, ow;
                #pragma unroll
                for (int j = 0; j < 4; ++j) {
                    const int i = k * 4 + j;
                    const float x0   = x0_[i];
                    const float s128 = s_[i] * 0.0078125f;
                    {
                        float xi = pa[i] - va;
                        xi = xi + floorf(xi * 0.5f) - floorf(xi * 0.0625f);
                        const float ei = exp_slow(xi, x0);
                        const float em = exp_slow(xmta, x0);
                        const float factor = floorf(F2_31 / fminf(ei + em, F2_31));
                        ov[j] = (pa[i] * floorf((ei * factor) * 0x1p-24f)) * s128;
                    }
                    {
                        float xi = pb[i] - vb;
                        xi = xi + floorf(xi * 0.5f) - floorf(xi * 0.0625f);
                        const float ei = exp_slow(xi, x0);
                        const float em = exp_slow(xmtb, x0);
                        const float factor = floorf(F2_31 / fminf(ei + em, F2_31));
                        ow[j] = (pb[i] * floorf((ei * factor) * 0x1p-24f)) * s128;
                    }
                }
                __builtin_nontemporal_store(
                    ov, reinterpret_cast<f32x4*>(out + base + (k ? c1 : c0)));
                if (bval)
                    __builtin_nontemporal_store(
                        ow, reinterpret_cast<f32x4*>(out + base + D + (k ? c1 : c0)));
            }
        }

        base += 2 * D;
    }
}

extern "C" void kernel_launch(void* const* d_in, const int* in_sizes, int n_in,
                              void* d_out, int out_size, void* d_ws, size_t ws_size,
                              hipStream_t stream) {
    const float* x      = (const float*)d_in[0];
    const float* scaler = (const float*)d_in[1];
    float* out          = (float*)d_out;

    const int nrows = in_sizes[0] / D;                 // 8192
    const int grid  = (nrows + RPB - 1) / RPB;         // 1024
    quantgelu_kernel<<<grid, BLK, 0, stream>>>(x, scaler, out, nrows);
}

// Round 8
// 49.368 us; speedup vs baseline: 2.2661x; 1.0751x over previous
//
#include <hip/hip_runtime.h>

// QuantGelu: y = pre_x_int * sigmoid_int * (scaler/128)
//   pre_x_int = clip(round(x/scaler), -128, 127)  [per-channel scaler, D=4096]
//   sigmoid via integer shift-exp over {x_int, -row_max}
//
// Round-8: software-pipelined rows, ONE barrier per row:
//   iter r: build sigt[r&1] (row r) | quantize row r+1 + wave-max | prefetch
//           row r+2  ->  barrier  ->  lookup+store row r, read vmax[r+1].
// Double-buffered sigt/smax give write/read separation (each buffer rewrite
// is 2 iters after its read with a barrier between; build writes are
// tid-partitioned). Single-row build + 1-row prefetch (round-5 lineage; the
// round-7 dual-row grouping regressed). Math identical -> bit-same output.

#define D 4096
#define BLK 512
#define CPT 8           // BLK*CPT == D
#define RPB 8
#define NW (BLK / 64)
#define NSLOT 12        // x0 slots covered by fast path
#define TENT (NSLOT * 256)
#define EPS 1e-4f
#define F2_31 2147483648.0f   // fl32(2^31 - 1)

typedef float f32x4 __attribute__((ext_vector_type(4)));

// Exact floor(fl(xi/x0)) for integer-valued xi, integer x0 in [-64,-1],
// clamped ratio in [0,15]: divisible case error << EPS; non-divisible case
// distance to integer >= 1/|x0| >= 1/64 >> EPS. ldexpf = v_ldexp_f32; q<0
// (em path) -> inf, matching np.exp2(15-q)=inf, absorbed by min(esum,2^31).
__device__ __forceinline__ float exp_fast(float xi, float nx0, float rx0) {
    const float q = floorf(fmaf(xi, rx0, EPS));
    const float r = fmaf(nx0, q, xi);      // xi - x0*q, exact (small ints)
    const float e = fmaf(r, 0.5f, nx0);    // r/2 - x0, halves, exact
    return floorf(ldexpf(e, 15 - (int)q)); // e > 0 -> max(.,0) redundant
}

// Fully-IEEE path, exact for any x0 (fallback only).
__device__ __forceinline__ float exp_slow(float xi, float x0) {
    xi = fmaxf(xi, 15.0f * x0);
    const float q = floorf(xi / x0);
    const float r = fmaf(-x0, q, xi);
    const float e = fmaf(r, 0.5f, -x0);
    return fmaxf(floorf(e * ldexpf(1.0f, 15 - (int)q)), 0.0f);
}

__global__ __launch_bounds__(BLK) void quantgelu_kernel(
    const float* __restrict__ x, const float* __restrict__ scaler,
    float* __restrict__ out, int nrows)
{
    const int tid  = threadIdx.x;
    const int wid  = tid >> 6;
    const int lane = tid & 63;
    const int row0 = blockIdx.x * RPB;

    __shared__ __align__(16) float smax2[2][NW];
    __shared__ float eit[TENT];
    __shared__ float sig2[2][TENT];

    const int c0 = tid * 4;
    const int c1 = BLK * 4 + tid * 4;

    // ---- prefetch row 0 ASAP ----
    float4 xv[2];
    if (row0 < nrows) {
        const long long b0 = (long long)row0 * D;
        xv[0] = *reinterpret_cast<const float4*>(x + b0 + c0);
        xv[1] = *reinterpret_cast<const float4*>(x + b0 + c1);
    }

    // ---- per-channel constants (hoisted across RPB rows) ----
    float s_[CPT], rs_[CPT];
    int   bo_[CPT];
    float x0mn, x0mx;
    {
        float x0t[CPT];
        #pragma unroll
        for (int k = 0; k < 2; ++k) {
            const float4 sv = *reinterpret_cast<const float4*>(scaler + (k ? c1 : c0));
            const float ss[4] = {sv.x, sv.y, sv.z, sv.w};
            #pragma unroll
            for (int j = 0; j < 4; ++j) {
                const int i = k * 4 + j;
                const float s = ss[j];
                s_[i]  = s;
                rs_[i] = 1.0f / s;                          // Markstein seed
                x0t[i] = floorf(-1.0f / (s * 1.702f));      // IEEE div, 1x/8 rows
            }
        }
        // block-wide x0 range
        x0mn = x0t[0]; x0mx = x0t[0];
        #pragma unroll
        for (int i = 1; i < CPT; ++i) {
            x0mn = fminf(x0mn, x0t[i]);
            x0mx = fmaxf(x0mx, x0t[i]);
        }
        #pragma unroll
        for (int off = 1; off < 64; off <<= 1) {
            x0mn = fminf(x0mn, __shfl_xor(x0mn, off));
            x0mx = fmaxf(x0mx, __shfl_xor(x0mx, off));
        }
        if (lane == 0) { smax2[0][wid] = x0mn; smax2[1][wid] = x0mx; }
        __syncthreads();
        #pragma unroll
        for (int w = 0; w < NW; ++w) {
            x0mn = fminf(x0mn, smax2[0][w]);
            x0mx = fmaxf(x0mx, smax2[1][w]);
        }
        __syncthreads();    // smax2 free for row-max reuse

        // slot offsets; x0t dead afterwards (fallback recomputes from s_)
        #pragma unroll
        for (int i = 0; i < CPT; ++i)
            bo_[i] = ((int)(x0t[i] - x0mn)) << 8;
    }

    const int  nslots = (int)(x0mx - x0mn) + 1;
    const bool ok = (x0mn >= -64.0f) && (nslots <= NSLOT);   // block-uniform
    const int  nent = nslots << 8;              // multiple of 256

    // lane-slot constants: lane l serves slot l
    const float x0l  = x0mn + (float)lane;
    const float nx0l = -x0l;
    const float rx0l = 1.0f / x0l;              // IEEE div, 1x per block
    const float c15l = 15.0f * x0l;

    // block-invariant ei table: ei(slot, d) = int_exp_shift(-d, x0_slot)
    if (ok) {
        for (int e = tid; e < nent; e += BLK) {
            const int   slot = e >> 8;
            const float x0v  = x0mn + (float)slot;
            float xi = -(float)(e & 255);
            xi = xi + floorf(xi * 0.5f) - floorf(xi * 0.0625f);
            xi = fmaxf(xi, 15.0f * x0v);
            eit[e] = exp_fast(xi, -x0v, __shfl(rx0l, slot));
        }
    }

    // ---- pipeline prologue: quantize row 0, publish its max ----
    float pre_c[CPT], pre_n[CPT];
    float vmax = -INFINITY;
    if (row0 < nrows) {
        #pragma unroll
        for (int k = 0; k < 2; ++k) {
            const float* xa = reinterpret_cast<const float*>(&xv[k]);
            #pragma unroll
            for (int j = 0; j < 4; ++j) {
                const int i = k * 4 + j;
                const float q0 = xa[j] * rs_[i];
                const float rr = fmaf(-s_[i], q0, xa[j]);
                const float p  = __builtin_amdgcn_fmed3f(
                                   rintf(fmaf(rr, rs_[i], q0)), -128.0f, 127.0f);
                pre_c[i] = p;
                vmax = fmaxf(vmax, p);
            }
        }
        #pragma unroll
        for (int off = 1; off < 64; off <<= 1)
            vmax = fmaxf(vmax, __shfl_xor(vmax, off));
        if (lane == 0) smax2[0][wid] = vmax;
        // prefetch row 1
        if (row0 + 1 < nrows) {
            const long long b1 = (long long)(row0 + 1) * D;
            xv[0] = *reinterpret_cast<const float4*>(x + b1 + c0);
            xv[1] = *reinterpret_cast<const float4*>(x + b1 + c1);
        }
    }
    __syncthreads();        // C: publishes eit + smax2[0]
    {
        const float4 a0 = *reinterpret_cast<const float4*>(&smax2[0][0]);
        const float4 a1 = *reinterpret_cast<const float4*>(&smax2[0][4]);
        vmax = fmaxf(fmaxf(fmaxf(a0.x, a0.y), fmaxf(a0.z, a0.w)),
                     fmaxf(fmaxf(a1.x, a1.y), fmaxf(a1.z, a1.w)));
    }

    for (int r = 0; r < RPB; ++r) {
        const int row = row0 + r;
        if (row >= nrows) break;                // block-uniform
        const bool hasnext = (r + 1 < RPB) && (row + 1 < nrows);
        const int  cur = r & 1, nxt = cur ^ 1;

        const float xm  = -vmax;
        const float xmt = xm + floorf(xm * 0.5f) - floorf(xm * 0.0625f);

        // build sig table for row r into sig2[cur] (scaler/128's 2^-7 folded:
        // sig integer <= 256 -> *2^-7 exact)
        if (ok) {
            const float em_l = exp_fast(fmaxf(xmt, c15l), nx0l, rx0l);
            for (int e = tid; e < nent; e += BLK) {
                const int   slot = e >> 8;      // wave-uniform (64 | 256)
                const float ei   = eit[e];
                const float em   = __shfl(em_l, slot);
                const float f    = floorf(F2_31 / fminf(ei + em, F2_31)); // IEEE div
                sig2[cur][e] = floorf((ei * f) * 0x1p-24f) * 0.0078125f;
            }
        }

        // quantize row r+1 + wave max, publish to smax2[nxt]
        if (hasnext) {
            float vnext = -INFINITY;
            #pragma unroll
            for (int k = 0; k < 2; ++k) {
                const float* xa = reinterpret_cast<const float*>(&xv[k]);
                #pragma unroll
                for (int j = 0; j < 4; ++j) {
                    const int i = k * 4 + j;
                    const float q0 = xa[j] * rs_[i];
                    const float rr = fmaf(-s_[i], q0, xa[j]);
                    const float p  = __builtin_amdgcn_fmed3f(
                                       rintf(fmaf(rr, rs_[i], q0)), -128.0f, 127.0f);
                    pre_n[i] = p;
                    vnext = fmaxf(vnext, p);
                }
            }
            #pragma unroll
            for (int off = 1; off < 64; off <<= 1)
                vnext = fmaxf(vnext, __shfl_xor(vnext, off));
            if (lane == 0) smax2[nxt][wid] = vnext;
            // prefetch row r+2
            if (r + 2 < RPB && row + 2 < nrows) {
                const long long b2 = (long long)(row + 2) * D;
                xv[0] = *reinterpret_cast<const float4*>(x + b2 + c0);
                xv[1] = *reinterpret_cast<const float4*>(x + b2 + c1);
            }
        }

        __syncthreads();    // publishes sig2[cur] (row r) AND smax2[nxt] (row r+1)

        // lookup + store row r
        const long long rb = (long long)row * D;
        if (ok) {
            #pragma unroll
            for (int k = 0; k < 2; ++k) {
                f32x4 ov;
                #pragma unroll
                for (int j = 0; j < 4; ++j) {
                    const int i = k * 4 + j;
                    const int d = (int)(vmax - pre_c[i]);       // exact, [0,255]
                    ov[j] = (pre_c[i] * sig2[cur][bo_[i] + d]) * s_[i];
                }
                __builtin_nontemporal_store(
                    ov, reinterpret_cast<f32x4*>(out + rb + (k ? c1 : c0)));
            }
        } else {
            // rare block-uniform exact fallback (x0 out of table range)
            #pragma unroll
            for (int k = 0; k < 2; ++k) {
                f32x4 ov;
                #pragma unroll
                for (int j = 0; j < 4; ++j) {
                    const int i = k * 4 + j;
                    const float x0 = floorf(-1.0f / (s_[i] * 1.702f));
                    float xi = pre_c[i] - vmax;
                    xi = xi + floorf(xi * 0.5f) - floorf(xi * 0.0625f);
                    const float ei = exp_slow(xi, x0);
                    const float em = exp_slow(xmt, x0);
                    const float factor = floorf(F2_31 / fminf(ei + em, F2_31));
                    ov[j] = (pre_c[i] * floorf((ei * factor) * 0x1p-24f))
                            * (s_[i] * 0.0078125f);
                }
                __builtin_nontemporal_store(
                    ov, reinterpret_cast<f32x4*>(out + rb + (k ? c1 : c0)));
            }
        }

        // advance pipeline
        if (hasnext) {
            const float4 a0 = *reinterpret_cast<const float4*>(&smax2[nxt][0]);
            const float4 a1 = *reinterpret_cast<const float4*>(&smax2[nxt][4]);
            vmax = fmaxf(fmaxf(fmaxf(a0.x, a0.y), fmaxf(a0.z, a0.w)),
                         fmaxf(fmaxf(a1.x, a1.y), fmaxf(a1.z, a1.w)));
            #pragma unroll
            for (int i = 0; i < CPT; ++i) pre_c[i] = pre_n[i];
        }
    }
}

extern "C" void kernel_launch(void* const* d_in, const int* in_sizes, int n_in,
                              void* d_out, int out_size, void* d_ws, size_t ws_size,
                              hipStream_t stream) {
    const float* x      = (const float*)d_in[0];
    const float* scaler = (const float*)d_in[1];
    float* out          = (float*)d_out;

    const int nrows = in_sizes[0] / D;                 // 8192
    const int grid  = (nrows + RPB - 1) / RPB;         // 1024
    quantgelu_kernel<<<grid, BLK, 0, stream>>>(x, scaler, out, nrows);
}